// Round 8
// baseline (232.441 us; speedup 1.0000x reference)
//
#include <hip/hip_runtime.h>
#include <math.h>

#define EDIM 256
#define LDIM 1024
#define HDIM 8
#define DDIM 32

typedef __attribute__((ext_vector_type(8))) short short8;
typedef __attribute__((ext_vector_type(2))) short short2v;
typedef __attribute__((ext_vector_type(4))) float f32x4;

__device__ inline unsigned short bf16h(float x) {
    unsigned u = __float_as_uint(x);
    return (unsigned short)((u + 0x7fff + ((u >> 16) & 1)) >> 16);   // RNE
}
__device__ inline float bf16tof(unsigned short h) {
    return __uint_as_float(((unsigned)h) << 16);
}
// native base-2 transcendentals (v_exp_f32: D=2^S0, v_log_f32: D=log2(S0)).
__device__ inline float exp2fast(float x) {
    float r; asm volatile("v_exp_f32 %0, %1" : "=v"(r) : "v"(x)); return r;
}
__device__ inline float log2fast(float x) {
    float r; asm volatile("v_log_f32 %0, %1" : "=v"(r) : "v"(x)); return r;
}

// base-2 softmax scale: 1/16 (energy/sqrt(E)) * log2(e)
#define SC2 0.09016843880556021f

#define NBLK 512

// Device-scope atomic grid barrier. Safe because all NBLK blocks are
// co-resident (launch_bounds(256,2), LDS 63.5KB -> exactly 2 blocks/CU on
// 256 CUs). Release fence BEFORE arrive makes our writes visible;
// acquire fence AFTER the spin invalidates stale local L1/L2 lines
// (the consumer-side fence R7's coop version was missing).
__device__ inline void grid_barrier(unsigned* cnt) {
    __syncthreads();
    if (threadIdx.x == 0) {
        __threadfence();                 // release
        atomicAdd(cnt, 1u);
        while (atomicAdd(cnt, 0u) < NBLK) __builtin_amdgcn_s_sleep(2);
    }
    __syncthreads();
    __threadfence();                     // acquire (invalidate stale lines)
}

// LDS union: attn phase (63.5 KB) dominates; proj/outproj reuse the space.
struct __align__(16) SmemProj {
    short Xhi[2][2][512], Xlo[2][2][512];
    short Whi[2][2][512], Wlo[2][2][512];
    float cpart[2][2][16];
};
struct __align__(16) SmemAttn {
    short vs_hi[4][32][72], vs_lo[4][32][72];   // per-wave V slice [d][krow]
    short pa_hi[4][16][72], pa_lo[4][16][72];   // per-wave P [q][krow]
    float mw[4][16], lw[4][16];
    float Ow[4][16][36];
};
union SmemU {
    SmemProj p;
    SmemAttn a;
};

// ---------------------------------------------------------------------------
// mega_kernel: plain launch, 512 blocks x 256 thr (2/CU co-resident).
// Phase 1: projections (1024 units, 2/block). Phase 2: full-K flash
// attention (512 units, 1/block). Phase 3: out-projection (256 units).
// Atomic grid barriers with release/acquire fences between phases.
// Phase internals identical to the verified R6 3-kernel version.
// ---------------------------------------------------------------------------
__global__ __launch_bounds__(256, 2) void mega_kernel(
    const float* __restrict__ Q, const float* __restrict__ Km, const float* __restrict__ V,
    const float* __restrict__ pos,
    const float* __restrict__ Wq, const float* __restrict__ Wk, const float* __restrict__ Wv,
    const float* __restrict__ Wr, const float* __restrict__ Wo, const float* __restrict__ bo,
    float* __restrict__ out, char* __restrict__ base)
{
    __shared__ SmemU sm;

    short* qThi  = (short*)(base);
    short* qTlo  = (short*)(base + 524288);
    short* kThi  = (short*)(base + 1048576);
    short* kTlo  = (short*)(base + 1572864);
    short* vThi  = (short*)(base + 2097152);
    short* vTlo  = (short*)(base + 2621440);
    float* coeff = (float*)(base + 3145728);
    short* Wohi  = (short*)(base + 3178496);
    short* Wolo  = (short*)(base + 3309568);
    short* Ahi   = (short*)(base + 3440640);
    short* Alo   = (short*)(base + 3964928);
    unsigned* flags = (unsigned*)(base + 4489216);   // zeroed by hipMemsetAsync

    const int tid = threadIdx.x;
    const int bid = blockIdx.x;

    const int wave = tid >> 6, lane = tid & 63;
    const int n = lane & 15, quad = lane >> 4;

    // ======================= phase 1: projections =======================
    {
        const int rh = wave & 1, oh = wave >> 1;
        const int s    = tid >> 7;
        const int r    = (tid >> 2) & 31;
        const int qd   = tid & 3;
        const int half = r >> 4;
        const int fl8  = ((r & 15) | (qd << 4)) * 8;

        for (int ui = 0; ui < 2; ++ui) {
            const int u = bid * 2 + ui;
            const int z = u >> 8;
            const int x = u & 31, y = (u >> 5) & 7;

            if (z == 3) {   // Wo hi/lo split (elementwise, no LDS)
                const int idx = ((y * 32 + x) << 8) + tid;
                const float w = Wo[idx];
                const unsigned short hh = bf16h(w);
                Wohi[idx] = (short)hh;
                Wolo[idx] = (short)bf16h(w - bf16tof(hh));
                continue;
            }

            const float* __restrict__ X = (z == 0) ? Q : (z == 1) ? Km : V;
            const float* __restrict__ W = (z == 0) ? Wq : (z == 1) ? Wk : Wv;
            short* __restrict__ dhi     = (z == 0) ? qThi : (z == 1) ? kThi : vThi;
            short* __restrict__ dlo     = (z == 0) ? qTlo : (z == 1) ? kTlo : vTlo;
            const int n0 = x * 32;
            const int o0 = y * 32;   // one head

            const float* xp = X + (n0 + r) * EDIM + s * 32 + qd * 8;
            const float* wp = W + (o0 + r) * EDIM + s * 32 + qd * 8;

            float4 xa0 = *(const float4*)xp, xa1 = *(const float4*)(xp + 4);
            float4 wa0 = *(const float4*)wp, wa1 = *(const float4*)(wp + 4);

            f32x4 acc = {0.f, 0.f, 0.f, 0.f};

            for (int kb = 0; kb < EDIM; kb += 64) {
                __syncthreads();   // previous compute done, LDS free
                {
                    float xv[8] = {xa0.x,xa0.y,xa0.z,xa0.w, xa1.x,xa1.y,xa1.z,xa1.w};
                    float wv[8] = {wa0.x,wa0.y,wa0.z,wa0.w, wa1.x,wa1.y,wa1.z,wa1.w};
                    short8 xh, xl, wh, wl;
                    #pragma unroll
                    for (int j = 0; j < 8; ++j) {
                        unsigned short xhh = bf16h(xv[j]);
                        unsigned short whh = bf16h(wv[j]);
                        xh[j] = (short)xhh; xl[j] = (short)bf16h(xv[j] - bf16tof(xhh));
                        wh[j] = (short)whh; wl[j] = (short)bf16h(wv[j] - bf16tof(whh));
                    }
                    *(short8*)&sm.p.Xhi[s][half][fl8] = xh;
                    *(short8*)&sm.p.Xlo[s][half][fl8] = xl;
                    *(short8*)&sm.p.Whi[s][half][fl8] = wh;
                    *(short8*)&sm.p.Wlo[s][half][fl8] = wl;
                }
                float4 xn0, xn1, wn0, wn1;
                if (kb + 64 < EDIM) {
                    xn0 = *(const float4*)(xp + kb + 64); xn1 = *(const float4*)(xp + kb + 68);
                    wn0 = *(const float4*)(wp + kb + 64); wn1 = *(const float4*)(wp + kb + 68);
                }
                __syncthreads();   // staged
                #pragma unroll
                for (int ss = 0; ss < 2; ++ss) {
                    short8 ah = *(const short8*)&sm.p.Xhi[ss][rh][lane*8];
                    short8 al = *(const short8*)&sm.p.Xlo[ss][rh][lane*8];
                    short8 bh = *(const short8*)&sm.p.Whi[ss][oh][lane*8];
                    short8 bl = *(const short8*)&sm.p.Wlo[ss][oh][lane*8];
                    acc = __builtin_amdgcn_mfma_f32_16x16x32_bf16(al, bh, acc, 0, 0, 0);
                    acc = __builtin_amdgcn_mfma_f32_16x16x32_bf16(ah, bl, acc, 0, 0, 0);
                    acc = __builtin_amdgcn_mfma_f32_16x16x32_bf16(ah, bh, acc, 0, 0, 0);
                }
                xa0 = xn0; xa1 = xn1; wa0 = wn0; wa1 = wn1;
            }

            // epilogue: D layout row = rh*16 + 4*quad + i, col = oh*16 + n.
            const int h  = o0 >> 5;
            const int og = oh * 16 + n;
            #pragma unroll
            for (int i = 0; i < 4; ++i) {
                const int row = rh * 16 + 4 * quad + i;
                const unsigned short hh = bf16h(acc[i]);
                dhi[(h * LDIM + n0 + row) * DDIM + og] = (short)hh;
                dlo[(h * LDIM + n0 + row) * DDIM + og] = (short)bf16h(acc[i] - bf16tof(hh));
            }

            if (z == 0) {   // coeff epilogue
                const float wr = Wr[o0 + og];
                #pragma unroll
                for (int i = 0; i < 4; ++i) {
                    float c = acc[i] * wr;
                    c += __shfl_xor(c, 1, 64);
                    c += __shfl_xor(c, 2, 64);
                    c += __shfl_xor(c, 4, 64);
                    c += __shfl_xor(c, 8, 64);
                    if (n == 0) sm.p.cpart[rh][oh][4*quad + i] = c;
                }
                __syncthreads();
                if (tid < 32)
                    coeff[h * LDIM + n0 + tid] = sm.p.cpart[tid >> 4][0][tid & 15]
                                               + sm.p.cpart[tid >> 4][1][tid & 15];
            }
        }
    }

    grid_barrier(&flags[0]);

    // ======================= phase 2: attention =========================
    {
        const int h  = bid >> 6;
        const int q0 = (bid & 63) * 16;

        const short8 qhi = *(const short8*)(qThi + (h*LDIM + q0 + n) * DDIM + quad*8);
        const short8 qlo = *(const short8*)(qTlo + (h*LDIM + q0 + n) * DDIM + quad*8);

        float pq[4], cq[4];
        #pragma unroll
        for (int i = 0; i < 4; ++i) {
            const int r = q0 + 4*quad + i;
            pq[i] = pos[r];
            cq[i] = coeff[h*LDIM + r] * 0.0625f;
        }

        float m[4], l[4];
        #pragma unroll
        for (int i = 0; i < 4; ++i) { m[i] = -INFINITY; l[i] = 0.f; }
        f32x4 of0 = {0.f,0.f,0.f,0.f}, of1 = {0.f,0.f,0.f,0.f};

        const int ktb = wave * 256;   // this wave's k-range
        #pragma unroll 1
        for (int t = 0; t < 4; ++t) {
            const int kt = ktb + t * 64;

            // stage V (wave-private slice; contiguous 64B loads)
            {
                const short* vh = vThi + (h*LDIM + kt + lane) * DDIM;
                const short* vl = vTlo + (h*LDIM + kt + lane) * DDIM;
                #pragma unroll
                for (int hf = 0; hf < 2; ++hf) {
                    short8 a0 = *(const short8*)(vh + hf*16);
                    short8 a1 = *(const short8*)(vh + hf*16 + 8);
                    short8 b0 = *(const short8*)(vl + hf*16);
                    short8 b1 = *(const short8*)(vl + hf*16 + 8);
                    #pragma unroll
                    for (int j = 0; j < 8; ++j) {
                        sm.a.vs_hi[wave][hf*16 + j][lane]     = a0[j];
                        sm.a.vs_hi[wave][hf*16 + 8 + j][lane] = a1[j];
                        sm.a.vs_lo[wave][hf*16 + j][lane]     = b0[j];
                        sm.a.vs_lo[wave][hf*16 + 8 + j][lane] = b1[j];
                    }
                }
            }

            // S = QK^T: K-fragments direct from global (frag-shaped layout)
            f32x4 Sf[4];
            #pragma unroll
            for (int t4 = 0; t4 < 4; ++t4) {
                const int off = (h*LDIM + kt + t4*16 + n) * DDIM + quad*8;
                short8 bh = *(const short8*)(kThi + off);
                short8 bl = *(const short8*)(kTlo + off);
                f32x4 acc = {0.f, 0.f, 0.f, 0.f};
                acc = __builtin_amdgcn_mfma_f32_16x16x32_bf16(qlo, bh, acc, 0, 0, 0);
                acc = __builtin_amdgcn_mfma_f32_16x16x32_bf16(qhi, bl, acc, 0, 0, 0);
                acc = __builtin_amdgcn_mfma_f32_16x16x32_bf16(qhi, bh, acc, 0, 0, 0);
                Sf[t4] = acc;
            }

            // bias + online softmax (base-2)
            float ev[4][4];
            float rmax[4] = {-INFINITY, -INFINITY, -INFINITY, -INFINITY};
            #pragma unroll
            for (int t4 = 0; t4 < 4; ++t4) {
                const float pkt = pos[kt + t4*16 + n];
                #pragma unroll
                for (int i = 0; i < 4; ++i) {
                    float s = fmaf(Sf[t4][i], SC2, cq[i] * log2fast(fabsf(pq[i] - pkt) + 1.f));
                    ev[t4][i] = s;
                    rmax[i] = fmaxf(rmax[i], s);
                }
            }
            #pragma unroll
            for (int off = 1; off < 16; off <<= 1)
                #pragma unroll
                for (int i = 0; i < 4; ++i)
                    rmax[i] = fmaxf(rmax[i], __shfl_xor(rmax[i], off, 64));

            float al[4], rsum[4];
            #pragma unroll
            for (int i = 0; i < 4; ++i) {
                const float mn = fmaxf(m[i], rmax[i]);
                al[i] = exp2fast(m[i] - mn);
                m[i] = mn;
                rsum[i] = 0.f;
            }
            #pragma unroll
            for (int t4 = 0; t4 < 4; ++t4)
                #pragma unroll
                for (int i = 0; i < 4; ++i) {
                    float e = exp2fast(ev[t4][i] - m[i]);
                    rsum[i] += e;
                    unsigned u = __float_as_uint(e);
                    sm.a.pa_hi[wave][4*quad + i][16*t4 + n] = (short)(u >> 16);
                    float r = e - __uint_as_float(u & 0xffff0000u);
                    sm.a.pa_lo[wave][4*quad + i][16*t4 + n] = (short)bf16h(r);
                }
            #pragma unroll
            for (int off = 1; off < 16; off <<= 1)
                #pragma unroll
                for (int i = 0; i < 4; ++i)
                    rsum[i] += __shfl_xor(rsum[i], off, 64);
            #pragma unroll
            for (int i = 0; i < 4; ++i) l[i] = l[i]*al[i] + rsum[i];

            #pragma unroll
            for (int i = 0; i < 4; ++i) { of0[i] *= al[i]; of1[i] *= al[i]; }

            // PV on MFMA from wave-private LDS
            #pragma unroll
            for (int ch = 0; ch < 2; ++ch) {
                short8 phi = *(const short8*)&sm.a.pa_hi[wave][n][ch*32 + quad*8];
                short8 plo = *(const short8*)&sm.a.pa_lo[wave][n][ch*32 + quad*8];
                #pragma unroll
                for (int dt = 0; dt < 2; ++dt) {
                    short8 vh8 = *(const short8*)&sm.a.vs_hi[wave][dt*16 + n][ch*32 + quad*8];
                    short8 vl8 = *(const short8*)&sm.a.vs_lo[wave][dt*16 + n][ch*32 + quad*8];
                    f32x4& of = dt ? of1 : of0;
                    of = __builtin_amdgcn_mfma_f32_16x16x32_bf16(plo, vh8, of, 0, 0, 0);
                    of = __builtin_amdgcn_mfma_f32_16x16x32_bf16(phi, vl8, of, 0, 0, 0);
                    of = __builtin_amdgcn_mfma_f32_16x16x32_bf16(phi, vh8, of, 0, 0, 0);
                }
            }
        }

        // in-block flash combine of the 4 wave partials
        #pragma unroll
        for (int i = 0; i < 4; ++i) {
            sm.a.Ow[wave][4*quad + i][n]      = of0[i];
            sm.a.Ow[wave][4*quad + i][16 + n] = of1[i];
        }
        if (n == 0) {
            #pragma unroll
            for (int i = 0; i < 4; ++i) {
                sm.a.mw[wave][4*quad + i] = m[i];
                sm.a.lw[wave][4*quad + i] = l[i];
            }
        }
        __syncthreads();

        {
            const int q  = tid >> 4;          // 0..15
            const int dp = (tid & 15) * 2;    // 0..30
            float M = fmaxf(fmaxf(sm.a.mw[0][q], sm.a.mw[1][q]),
                            fmaxf(sm.a.mw[2][q], sm.a.mw[3][q]));
            float sc[4], s = 0.f;
            #pragma unroll
            for (int w = 0; w < 4; ++w) {
                sc[w] = exp2fast(sm.a.mw[w][q] - M);
                s += sc[w] * sm.a.lw[w][q];
            }
            const float inv = 1.f / s;
            short2v h2, l2;
            #pragma unroll
            for (int e = 0; e < 2; ++e) {
                float a = 0.f;
                #pragma unroll
                for (int w = 0; w < 4; ++w) a += sc[w] * sm.a.Ow[w][q][dp + e];
                a *= inv;
                const unsigned short hh = bf16h(a);
                h2[e] = (short)hh;
                l2[e] = (short)bf16h(a - bf16tof(hh));
            }
            *(short2v*)(Ahi + (q0 + q)*EDIM + h*DDIM + dp) = h2;
            *(short2v*)(Alo + (q0 + q)*EDIM + h*DDIM + dp) = l2;
        }
    }

    grid_barrier(&flags[1]);

    // ======================= phase 3: out-projection ====================
    if (bid < 256) {
        const int n0 = (bid & 31) * 32;
        const int o0 = (bid >> 5) * 32;
        const int rh = wave & 1, oh = wave >> 1;

        const int s    = tid >> 7;
        const int r    = (tid >> 2) & 31;
        const int qd   = tid & 3;
        const int half = r >> 4;
        const int fl8  = ((r & 15) | (qd << 4)) * 8;

        const short* xph = Ahi  + (n0 + r) * EDIM + s * 32 + qd * 8;
        const short* xpl = Alo  + (n0 + r) * EDIM + s * 32 + qd * 8;
        const short* wph = Wohi + (o0 + r) * EDIM + s * 32 + qd * 8;
        const short* wpl = Wolo + (o0 + r) * EDIM + s * 32 + qd * 8;

        short8 xh_c = *(const short8*)xph;
        short8 xl_c = *(const short8*)xpl;
        short8 wh_c = *(const short8*)wph;
        short8 wl_c = *(const short8*)wpl;

        f32x4 acc = {0.f, 0.f, 0.f, 0.f};

        for (int kb = 0; kb < EDIM; kb += 64) {
            __syncthreads();   // previous compute done, LDS free
            *(short8*)&sm.p.Xhi[s][half][fl8] = xh_c;
            *(short8*)&sm.p.Xlo[s][half][fl8] = xl_c;
            *(short8*)&sm.p.Whi[s][half][fl8] = wh_c;
            *(short8*)&sm.p.Wlo[s][half][fl8] = wl_c;
            short8 xh_n, xl_n, wh_n, wl_n;
            if (kb + 64 < EDIM) {
                xh_n = *(const short8*)(xph + kb + 64);
                xl_n = *(const short8*)(xpl + kb + 64);
                wh_n = *(const short8*)(wph + kb + 64);
                wl_n = *(const short8*)(wpl + kb + 64);
            }
            __syncthreads();   // staged
            #pragma unroll
            for (int ss = 0; ss < 2; ++ss) {
                short8 ah = *(const short8*)&sm.p.Xhi[ss][rh][lane*8];
                short8 al = *(const short8*)&sm.p.Xlo[ss][rh][lane*8];
                short8 bh = *(const short8*)&sm.p.Whi[ss][oh][lane*8];
                short8 bl = *(const short8*)&sm.p.Wlo[ss][oh][lane*8];
                acc = __builtin_amdgcn_mfma_f32_16x16x32_bf16(al, bh, acc, 0, 0, 0);
                acc = __builtin_amdgcn_mfma_f32_16x16x32_bf16(ah, bl, acc, 0, 0, 0);
                acc = __builtin_amdgcn_mfma_f32_16x16x32_bf16(ah, bh, acc, 0, 0, 0);
            }
            xh_c = xh_n; xl_c = xl_n; wh_c = wh_n; wl_c = wl_n;
        }

        const int og = o0 + oh*16 + n;
        const float b = bo[og];
        #pragma unroll
        for (int i = 0; i < 4; ++i) {
            const int row = n0 + rh*16 + 4*quad + i;
            out[row * EDIM + og] = acc[i] + b;
        }
    }
}

// ---------------------------------------------------------------------------
extern "C" void kernel_launch(void* const* d_in, const int* in_sizes, int n_in,
                              void* d_out, int out_size, void* d_ws, size_t ws_size,
                              hipStream_t stream) {
    const float* V   = (const float*)d_in[0];
    const float* K   = (const float*)d_in[1];
    const float* Q   = (const float*)d_in[2];
    const float* pos = (const float*)d_in[3];
    const float* Wq  = (const float*)d_in[4];
    const float* Wk  = (const float*)d_in[5];
    const float* Wv  = (const float*)d_in[6];
    const float* Wr  = (const float*)d_in[7];
    const float* Wo  = (const float*)d_in[8];
    const float* bo  = (const float*)d_in[9];
    float* out = (float*)d_out;
    char* base = (char*)d_ws;
    // data region: [0, 4489216); barrier flags at 4489216 (zeroed per replay)

    hipMemsetAsync(base + 4489216, 0, 64, stream);
    mega_kernel<<<dim3(NBLK), dim3(256), 0, stream>>>(
        Q, K, V, pos, Wq, Wk, Wv, Wr, Wo, bo, out, base);
}

// Round 9
// 101.251 us; speedup vs baseline: 2.2957x; 2.2957x over previous
//
#include <hip/hip_runtime.h>
#include <math.h>

#define EDIM 256
#define LDIM 1024
#define HDIM 8
#define DDIM 32

typedef __attribute__((ext_vector_type(8))) short short8;
typedef __attribute__((ext_vector_type(2))) short short2v;
typedef __attribute__((ext_vector_type(4))) short shortx4;
typedef __attribute__((ext_vector_type(4))) float f32x4;

__device__ inline unsigned short bf16h(float x) {
    unsigned u = __float_as_uint(x);
    return (unsigned short)((u + 0x7fff + ((u >> 16) & 1)) >> 16);   // RNE
}
__device__ inline float bf16tof(unsigned short h) {
    return __uint_as_float(((unsigned)h) << 16);
}
// native base-2 transcendentals (v_exp_f32: D=2^S0, v_log_f32: D=log2(S0)).
// Inline asm avoids the glibc __exp2f/__log2f reserved-identifier collision.
__device__ inline float exp2fast(float x) {
    float r; asm volatile("v_exp_f32 %0, %1" : "=v"(r) : "v"(x)); return r;
}
__device__ inline float log2fast(float x) {
    float r; asm volatile("v_log_f32 %0, %1" : "=v"(r) : "v"(x)); return r;
}

// base-2 softmax scale: 1/16 (energy/sqrt(E)) * log2(e)
#define SC2 0.09016843880556021f

// ---------------------------------------------------------------------------
// proj_kernel (MFMA): z<3: dst(H,L,D) = X(L,E) @ W(E,E)^T, outputs written as
// SEPARATE hi/lo bf16 short arrays (consumers do zero unpack ALU). 32x32
// tile, 4 waves x one 16x16 frag, BK=64, split-bf16 3-term. z==0 also fuses
// coeff[h][n] = sum_d q[n,h,d]*Wr[h*32+d]. z==3: split Wo into Wohi/Wolo
// for the outproj kernel (one elem per thread, 256 blocks).
// ---------------------------------------------------------------------------
__global__ __launch_bounds__(256) void proj_kernel(
    const float* __restrict__ Q, const float* __restrict__ Km, const float* __restrict__ V,
    const float* __restrict__ Wq, const float* __restrict__ Wk, const float* __restrict__ Wv,
    const float* __restrict__ Wr, const float* __restrict__ Wo,
    short* __restrict__ qThi, short* __restrict__ qTlo,
    short* __restrict__ kThi, short* __restrict__ kTlo,
    short* __restrict__ vThi, short* __restrict__ vTlo,
    float* __restrict__ coeff, short* __restrict__ Wohi, short* __restrict__ Wolo)
{
    const int z = blockIdx.z;
    const int tid = threadIdx.x;

    if (z == 3) {   // Wo hi/lo split prep (256 blocks x 256 thr = 65536 elems)
        const int idx = ((blockIdx.y * 32 + blockIdx.x) << 8) + tid;
        const float w = Wo[idx];
        const unsigned short hh = bf16h(w);
        Wohi[idx] = (short)hh;
        Wolo[idx] = (short)bf16h(w - bf16tof(hh));
        return;
    }

    const float* __restrict__ X = (z == 0) ? Q : (z == 1) ? Km : V;
    const float* __restrict__ W = (z == 0) ? Wq : (z == 1) ? Wk : Wv;
    short* __restrict__ dhi     = (z == 0) ? qThi : (z == 1) ? kThi : vThi;
    short* __restrict__ dlo     = (z == 0) ? qTlo : (z == 1) ? kTlo : vTlo;

    const int n0 = blockIdx.x * 32;
    const int o0 = blockIdx.y * 32;   // one head: o0 = h*32
    const int wave = tid >> 6, lane = tid & 63;
    const int n = lane & 15, quad = lane >> 4;
    const int rh = wave & 1, oh = wave >> 1;   // wave's row-half / col-half

    // staging role: K-slice s (32 wide), row r (0..31), k-quad qd (8 elems)
    const int s    = tid >> 7;
    const int r    = (tid >> 2) & 31;
    const int qd   = tid & 3;
    const int half = r >> 4;
    const int fl8  = ((r & 15) | (qd << 4)) * 8;   // frag-lane * 8

    __shared__ short Xhi[2][2][512], Xlo[2][2][512];   // [slice][row-half][lane*8]
    __shared__ short Whi[2][2][512], Wlo[2][2][512];
    __shared__ float cpart[2][2][16];

    const float* xp = X + (n0 + r) * EDIM + s * 32 + qd * 8;
    const float* wp = W + (o0 + r) * EDIM + s * 32 + qd * 8;

    float4 xa0 = *(const float4*)xp, xa1 = *(const float4*)(xp + 4);
    float4 wa0 = *(const float4*)wp, wa1 = *(const float4*)(wp + 4);

    f32x4 acc = {0.f, 0.f, 0.f, 0.f};

    for (int kb = 0; kb < EDIM; kb += 64) {
        __syncthreads();   // previous compute done, LDS free
        {
            float xv[8] = {xa0.x,xa0.y,xa0.z,xa0.w, xa1.x,xa1.y,xa1.z,xa1.w};
            float wv[8] = {wa0.x,wa0.y,wa0.z,wa0.w, wa1.x,wa1.y,wa1.z,wa1.w};
            short8 xh, xl, wh, wl;
            #pragma unroll
            for (int j = 0; j < 8; ++j) {
                unsigned short xhh = bf16h(xv[j]);
                unsigned short whh = bf16h(wv[j]);
                xh[j] = (short)xhh; xl[j] = (short)bf16h(xv[j] - bf16tof(xhh));
                wh[j] = (short)whh; wl[j] = (short)bf16h(wv[j] - bf16tof(whh));
            }
            *(short8*)&Xhi[s][half][fl8] = xh;
            *(short8*)&Xlo[s][half][fl8] = xl;
            *(short8*)&Whi[s][half][fl8] = wh;
            *(short8*)&Wlo[s][half][fl8] = wl;
        }
        float4 xn0, xn1, wn0, wn1;
        if (kb + 64 < EDIM) {
            xn0 = *(const float4*)(xp + kb + 64); xn1 = *(const float4*)(xp + kb + 68);
            wn0 = *(const float4*)(wp + kb + 64); wn1 = *(const float4*)(wp + kb + 68);
        }
        __syncthreads();   // staged
        #pragma unroll
        for (int ss = 0; ss < 2; ++ss) {
            short8 ah = *(const short8*)&Xhi[ss][rh][lane*8];
            short8 al = *(const short8*)&Xlo[ss][rh][lane*8];
            short8 bh = *(const short8*)&Whi[ss][oh][lane*8];
            short8 bl = *(const short8*)&Wlo[ss][oh][lane*8];
            acc = __builtin_amdgcn_mfma_f32_16x16x32_bf16(al, bh, acc, 0, 0, 0);
            acc = __builtin_amdgcn_mfma_f32_16x16x32_bf16(ah, bl, acc, 0, 0, 0);
            acc = __builtin_amdgcn_mfma_f32_16x16x32_bf16(ah, bh, acc, 0, 0, 0);
        }
        xa0 = xn0; xa1 = xn1; wa0 = wn0; wa1 = wn1;
    }

    // epilogue: D layout row = rh*16 + 4*quad + i, col = oh*16 + n.
    const int h  = o0 >> 5;
    const int og = oh * 16 + n;
    #pragma unroll
    for (int i = 0; i < 4; ++i) {
        const int row = rh * 16 + 4 * quad + i;
        const unsigned short hh = bf16h(acc[i]);
        dhi[(h * LDIM + n0 + row) * DDIM + og] = (short)hh;
        dlo[(h * LDIM + n0 + row) * DDIM + og] = (short)bf16h(acc[i] - bf16tof(hh));
    }

    if (z == 0) {   // coeff[h][n] = sum over d (all 32 cols = 2 waves x 16 lanes)
        const float wr = Wr[o0 + og];
        #pragma unroll
        for (int i = 0; i < 4; ++i) {
            float c = acc[i] * wr;
            c += __shfl_xor(c, 1, 64);
            c += __shfl_xor(c, 2, 64);
            c += __shfl_xor(c, 4, 64);
            c += __shfl_xor(c, 8, 64);
            if (n == 0) cpart[rh][oh][4*quad + i] = c;
        }
        __syncthreads();
        if (tid < 32)
            coeff[h * LDIM + n0 + tid] = cpart[tid >> 4][0][tid & 15]
                                       + cpart[tid >> 4][1][tid & 15];
    }
}

// ---------------------------------------------------------------------------
// attn_kernel: FULL-K flash attention per block -> no cross-block partials,
// no combine kernel, no Op/Mp/Lp traffic. Grid (64,8) = 512 blocks (2/CU):
// 16 q-rows per block, 4 waves; wave w owns k-range [w*256, w*256+256)
// (4 tiles of 64) with its own online softmax. ZERO barriers in the main
// loop: V/P LDS slices are wave-private; K-fragments are read DIRECT from
// global (kThi layout is already fragment-shaped; L2-resident). One
// __syncthreads at the end merges the 4 wave-partials (in-block flash
// combine) and writes normalized A as split hi/lo for outproj.
// ---------------------------------------------------------------------------
__global__ __launch_bounds__(256, 2) void attn_kernel(
    const short* __restrict__ qThi, const short* __restrict__ qTlo,
    const short* __restrict__ kThi, const short* __restrict__ kTlo,
    const short* __restrict__ vThi, const short* __restrict__ vTlo,
    const float* __restrict__ coeff, const float* __restrict__ pos,
    short* __restrict__ Ahi, short* __restrict__ Alo)
{
    const int h    = blockIdx.y;
    const int q0   = blockIdx.x * 16;
    const int tid  = threadIdx.x;
    const int wave = tid >> 6;
    const int lane = tid & 63;
    const int n    = lane & 15;
    const int quad = lane >> 4;

    __shared__ __align__(16) short vs_hi[4][32][72];   // per-wave V slice [d][krow]
    __shared__ __align__(16) short vs_lo[4][32][72];
    __shared__ __align__(16) short pa_hi[4][16][72];   // per-wave P [q][krow]
    __shared__ __align__(16) short pa_lo[4][16][72];
    __shared__ float mw[4][16], lw[4][16];             // wave-partial m, l
    __shared__ float Ow[4][16][36];                    // wave-partial O

    // ---- Q fragment (same 16 rows for all waves) ----
    const short8 qhi = *(const short8*)(qThi + (h*LDIM + q0 + n) * DDIM + quad*8);
    const short8 qlo = *(const short8*)(qTlo + (h*LDIM + q0 + n) * DDIM + quad*8);

    float pq[4], cq[4];
    #pragma unroll
    for (int i = 0; i < 4; ++i) {
        const int r = q0 + 4*quad + i;
        pq[i] = pos[r];
        cq[i] = coeff[h*LDIM + r] * 0.0625f;
    }

    float m[4], l[4];
    #pragma unroll
    for (int i = 0; i < 4; ++i) { m[i] = -INFINITY; l[i] = 0.f; }
    f32x4 of0 = {0.f,0.f,0.f,0.f}, of1 = {0.f,0.f,0.f,0.f};

    const int ktb = wave * 256;   // this wave's k-range
    #pragma unroll 1
    for (int t = 0; t < 4; ++t) {
        const int kt = ktb + t * 64;

        // ---- stage V: lane stages krow kt+lane (contiguous 64B loads,
        //      2-way-free scalar stores into wave-private slice) ----
        {
            const short* vh = vThi + (h*LDIM + kt + lane) * DDIM;
            const short* vl = vTlo + (h*LDIM + kt + lane) * DDIM;
            #pragma unroll
            for (int hf = 0; hf < 2; ++hf) {
                short8 a0 = *(const short8*)(vh + hf*16);
                short8 a1 = *(const short8*)(vh + hf*16 + 8);
                short8 b0 = *(const short8*)(vl + hf*16);
                short8 b1 = *(const short8*)(vl + hf*16 + 8);
                #pragma unroll
                for (int j = 0; j < 8; ++j) {
                    vs_hi[wave][hf*16 + j][lane]     = a0[j];
                    vs_hi[wave][hf*16 + 8 + j][lane] = a1[j];
                    vs_lo[wave][hf*16 + j][lane]     = b0[j];
                    vs_lo[wave][hf*16 + 8 + j][lane] = b1[j];
                }
            }
        }

        // ---- S = QK^T: K-fragments direct from global (frag-shaped layout) ----
        f32x4 Sf[4];
        #pragma unroll
        for (int t4 = 0; t4 < 4; ++t4) {
            const int off = (h*LDIM + kt + t4*16 + n) * DDIM + quad*8;
            short8 bh = *(const short8*)(kThi + off);
            short8 bl = *(const short8*)(kTlo + off);
            f32x4 acc = {0.f, 0.f, 0.f, 0.f};
            acc = __builtin_amdgcn_mfma_f32_16x16x32_bf16(qlo, bh, acc, 0, 0, 0);
            acc = __builtin_amdgcn_mfma_f32_16x16x32_bf16(qhi, bl, acc, 0, 0, 0);
            acc = __builtin_amdgcn_mfma_f32_16x16x32_bf16(qhi, bh, acc, 0, 0, 0);
            Sf[t4] = acc;
        }

        // ---- bias + online softmax (base-2) ----
        float ev[4][4];
        float rmax[4] = {-INFINITY, -INFINITY, -INFINITY, -INFINITY};
        #pragma unroll
        for (int t4 = 0; t4 < 4; ++t4) {
            const float pkt = pos[kt + t4*16 + n];
            #pragma unroll
            for (int i = 0; i < 4; ++i) {
                float s = fmaf(Sf[t4][i], SC2, cq[i] * log2fast(fabsf(pq[i] - pkt) + 1.f));
                ev[t4][i] = s;
                rmax[i] = fmaxf(rmax[i], s);
            }
        }
        #pragma unroll
        for (int off = 1; off < 16; off <<= 1)
            #pragma unroll
            for (int i = 0; i < 4; ++i)
                rmax[i] = fmaxf(rmax[i], __shfl_xor(rmax[i], off, 64));

        float al[4], rsum[4];
        #pragma unroll
        for (int i = 0; i < 4; ++i) {
            const float mn = fmaxf(m[i], rmax[i]);
            al[i] = exp2fast(m[i] - mn);
            m[i] = mn;
            rsum[i] = 0.f;
        }
        // exp2, row-sum, split-write P into wave-private slice
        #pragma unroll
        for (int t4 = 0; t4 < 4; ++t4)
            #pragma unroll
            for (int i = 0; i < 4; ++i) {
                float e = exp2fast(ev[t4][i] - m[i]);
                rsum[i] += e;
                unsigned u = __float_as_uint(e);
                pa_hi[wave][4*quad + i][16*t4 + n] = (short)(u >> 16);
                float r = e - __uint_as_float(u & 0xffff0000u);
                pa_lo[wave][4*quad + i][16*t4 + n] = (short)bf16h(r);
            }
        #pragma unroll
        for (int off = 1; off < 16; off <<= 1)
            #pragma unroll
            for (int i = 0; i < 4; ++i)
                rsum[i] += __shfl_xor(rsum[i], off, 64);
        #pragma unroll
        for (int i = 0; i < 4; ++i) l[i] = l[i]*al[i] + rsum[i];

        // in-register O rescale (rows 4*quad+i match al rows)
        #pragma unroll
        for (int i = 0; i < 4; ++i) { of0[i] *= al[i]; of1[i] *= al[i]; }

        // ---- PV on MFMA from wave-private LDS ----
        #pragma unroll
        for (int ch = 0; ch < 2; ++ch) {
            short8 phi = *(const short8*)&pa_hi[wave][n][ch*32 + quad*8];
            short8 plo = *(const short8*)&pa_lo[wave][n][ch*32 + quad*8];
            #pragma unroll
            for (int dt = 0; dt < 2; ++dt) {
                short8 vh8 = *(const short8*)&vs_hi[wave][dt*16 + n][ch*32 + quad*8];
                short8 vl8 = *(const short8*)&vs_lo[wave][dt*16 + n][ch*32 + quad*8];
                f32x4& of = dt ? of1 : of0;
                of = __builtin_amdgcn_mfma_f32_16x16x32_bf16(plo, vh8, of, 0, 0, 0);
                of = __builtin_amdgcn_mfma_f32_16x16x32_bf16(phi, vl8, of, 0, 0, 0);
                of = __builtin_amdgcn_mfma_f32_16x16x32_bf16(phi, vh8, of, 0, 0, 0);
            }
        }
    }

    // ---- in-block flash combine of the 4 wave partials ----
    #pragma unroll
    for (int i = 0; i < 4; ++i) {
        Ow[wave][4*quad + i][n]      = of0[i];
        Ow[wave][4*quad + i][16 + n] = of1[i];
    }
    if (n == 0) {
        #pragma unroll
        for (int i = 0; i < 4; ++i) {
            mw[wave][4*quad + i] = m[i];
            lw[wave][4*quad + i] = l[i];
        }
    }
    __syncthreads();   // the only barrier

    {
        const int q  = tid >> 4;          // 0..15
        const int dp = (tid & 15) * 2;    // 0..30
        float M = fmaxf(fmaxf(mw[0][q], mw[1][q]), fmaxf(mw[2][q], mw[3][q]));
        float sc[4], s = 0.f;
        #pragma unroll
        for (int w = 0; w < 4; ++w) {
            sc[w] = exp2fast(mw[w][q] - M);
            s += sc[w] * lw[w][q];
        }
        const float inv = 1.f / s;
        short2v h2, l2;
        #pragma unroll
        for (int e = 0; e < 2; ++e) {
            float a = 0.f;
            #pragma unroll
            for (int w = 0; w < 4; ++w) a += sc[w] * Ow[w][q][dp + e];
            a *= inv;
            const unsigned short hh = bf16h(a);
            h2[e] = (short)hh;
            l2[e] = (short)bf16h(a - bf16tof(hh));
        }
        *(short2v*)(Ahi + (q0 + q)*EDIM + h*DDIM + dp) = h2;
        *(short2v*)(Alo + (q0 + q)*EDIM + h*DDIM + dp) = l2;
    }
}

// ---------------------------------------------------------------------------
// outproj_kernel (MFMA): out(L,E) = A(L,E) @ Wo(E,E)^T + bo. A and Wo are
// both PRE-SPLIT hi/lo short arrays -> LDS staging is a pure copy (zero
// conversion ALU). 32x32 tiles, 4 waves x one 16x16 frag, BK=64, 3-term,
// grid (32,8)=256 blocks, software-pipelined.
// ---------------------------------------------------------------------------
__global__ __launch_bounds__(256) void outproj_kernel(
    const short* __restrict__ Ahi, const short* __restrict__ Alo,
    const short* __restrict__ Wohi, const short* __restrict__ Wolo,
    const float* __restrict__ bo, float* __restrict__ out)
{
    const int n0 = blockIdx.x * 32;
    const int o0 = blockIdx.y * 32;
    const int tid = threadIdx.x;
    const int wave = tid >> 6, lane = tid & 63;
    const int n = lane & 15, quad = lane >> 4;
    const int rh = wave & 1, oh = wave >> 1;

    const int s    = tid >> 7;
    const int r    = (tid >> 2) & 31;
    const int qd   = tid & 3;
    const int half = r >> 4;
    const int fl8  = ((r & 15) | (qd << 4)) * 8;

    __shared__ short Xhi[2][2][512], Xlo[2][2][512];
    __shared__ short Whi[2][2][512], Wlo[2][2][512];

    const short* xph = Ahi  + (n0 + r) * EDIM + s * 32 + qd * 8;
    const short* xpl = Alo  + (n0 + r) * EDIM + s * 32 + qd * 8;
    const short* wph = Wohi + (o0 + r) * EDIM + s * 32 + qd * 8;
    const short* wpl = Wolo + (o0 + r) * EDIM + s * 32 + qd * 8;

    short8 xh_c = *(const short8*)xph;
    short8 xl_c = *(const short8*)xpl;
    short8 wh_c = *(const short8*)wph;
    short8 wl_c = *(const short8*)wpl;

    f32x4 acc = {0.f, 0.f, 0.f, 0.f};

    for (int kb = 0; kb < EDIM; kb += 64) {
        __syncthreads();   // previous compute done, LDS free
        *(short8*)&Xhi[s][half][fl8] = xh_c;
        *(short8*)&Xlo[s][half][fl8] = xl_c;
        *(short8*)&Whi[s][half][fl8] = wh_c;
        *(short8*)&Wlo[s][half][fl8] = wl_c;
        short8 xh_n, xl_n, wh_n, wl_n;
        if (kb + 64 < EDIM) {
            xh_n = *(const short8*)(xph + kb + 64);
            xl_n = *(const short8*)(xpl + kb + 64);
            wh_n = *(const short8*)(wph + kb + 64);
            wl_n = *(const short8*)(wpl + kb + 64);
        }
        __syncthreads();   // staged
        #pragma unroll
        for (int ss = 0; ss < 2; ++ss) {
            short8 ah = *(const short8*)&Xhi[ss][rh][lane*8];
            short8 al = *(const short8*)&Xlo[ss][rh][lane*8];
            short8 bh = *(const short8*)&Whi[ss][oh][lane*8];
            short8 bl = *(const short8*)&Wlo[ss][oh][lane*8];
            acc = __builtin_amdgcn_mfma_f32_16x16x32_bf16(al, bh, acc, 0, 0, 0);
            acc = __builtin_amdgcn_mfma_f32_16x16x32_bf16(ah, bl, acc, 0, 0, 0);
            acc = __builtin_amdgcn_mfma_f32_16x16x32_bf16(ah, bh, acc, 0, 0, 0);
        }
        xh_c = xh_n; xl_c = xl_n; wh_c = wh_n; wl_c = wl_n;
    }

    const int og = o0 + oh*16 + n;
    const float b = bo[og];
    #pragma unroll
    for (int i = 0; i < 4; ++i) {
        const int row = n0 + rh*16 + 4*quad + i;
        out[row * EDIM + og] = acc[i] + b;
    }
}

// ---------------------------------------------------------------------------
extern "C" void kernel_launch(void* const* d_in, const int* in_sizes, int n_in,
                              void* d_out, int out_size, void* d_ws, size_t ws_size,
                              hipStream_t stream) {
    const float* V   = (const float*)d_in[0];
    const float* K   = (const float*)d_in[1];
    const float* Q   = (const float*)d_in[2];
    const float* pos = (const float*)d_in[3];
    const float* Wq  = (const float*)d_in[4];
    const float* Wk  = (const float*)d_in[5];
    const float* Wv  = (const float*)d_in[6];
    const float* Wr  = (const float*)d_in[7];
    const float* Wo  = (const float*)d_in[8];
    const float* bo  = (const float*)d_in[9];
    float* out = (float*)d_out;
    char* base = (char*)d_ws;

    short* qThi  = (short*)(base);
    short* qTlo  = (short*)(base + 524288);
    short* kThi  = (short*)(base + 1048576);
    short* kTlo  = (short*)(base + 1572864);
    short* vThi  = (short*)(base + 2097152);
    short* vTlo  = (short*)(base + 2621440);
    float* coeff = (float*)(base + 3145728);
    short* Wohi  = (short*)(base + 3178496);
    short* Wolo  = (short*)(base + 3309568);
    short* Ahi   = (short*)(base + 3440640);
    short* Alo   = (short*)(base + 3964928);
    // total workspace use: 4489216 bytes (harness provides >= 12 MB)

    proj_kernel   <<<dim3(32, 8, 4), 256, 0, stream>>>(Q, K, V, Wq, Wk, Wv, Wr, Wo,
                                                       qThi, qTlo, kThi, kTlo, vThi, vTlo,
                                                       coeff, Wohi, Wolo);
    attn_kernel   <<<dim3(64, 8),    256, 0, stream>>>(qThi, qTlo, kThi, kTlo, vThi, vTlo,
                                                       coeff, pos, Ahi, Alo);
    outproj_kernel<<<dim3(32, 8),    256, 0, stream>>>(Ahi, Alo, Wohi, Wolo, bo, out);
}